// Round 2
// baseline (561.027 us; speedup 1.0000x reference)
//
#include <hip/hip_runtime.h>
#include <cstdint>

#define NT 512
#define MT 8

// ws float offsets
static constexpr int C0_OFF = 0;          // conn0: 8*32*325 = 83200
static constexpr int C1_OFF = 83200;      // conn1: 50*26*52 = 67600
static constexpr int C2_OFF = 150800;     // conn2: 67600
static constexpr int CF_OFF = 218400;     // gate coeffs: 3*1300*4 = 15600

// ---------------------------------------------------------------------------
// Precompute: softmax the interconnect weights (axis=1) and collapse the
// 16-gate softmax-weighted bank to 4 affine coefficients per column:
//   gate16(A,B) = alpha + beta*A + gamma*B + delta*(A*B)
// ---------------------------------------------------------------------------
__global__ void precompute_kernel(const float* __restrict__ c0,
                                  const float* __restrict__ w0,
                                  const float* __restrict__ c1,
                                  const float* __restrict__ w1,
                                  const float* __restrict__ c2,
                                  const float* __restrict__ w2,
                                  float* __restrict__ ws) {
  int id = blockIdx.x * blockDim.x + threadIdx.x;
  if (id < 2600) {  // conn0 columns (n,o): softmax over m=32, stride 325
    int n = id / 325, o = id - n * 325;
    const float* src = c0 + n * (32 * 325) + o;
    float v[32]; float mx = -3.4e38f;
#pragma unroll
    for (int m = 0; m < 32; ++m) { v[m] = src[m * 325]; mx = fmaxf(mx, v[m]); }
    float ssum = 0.f;
#pragma unroll
    for (int m = 0; m < 32; ++m) { v[m] = __expf(v[m] - mx); ssum += v[m]; }
    float inv = 1.f / ssum;
    float* dst = ws + C0_OFF + n * (32 * 325) + o;
#pragma unroll
    for (int m = 0; m < 32; ++m) dst[m * 325] = v[m] * inv;
    return;
  }
  id -= 2600;
  if (id < 5200) {  // conn1 / conn2 columns: softmax over m=26, stride 52
    const float* src0 = (id < 2600) ? c1 : c2;
    float* dst0 = ws + ((id < 2600) ? C1_OFF : C2_OFF);
    int col = (id < 2600) ? id : id - 2600;
    int n = col / 52, o = col - n * 52;
    const float* src = src0 + n * (26 * 52) + o;
    float v[26]; float mx = -3.4e38f;
#pragma unroll
    for (int m = 0; m < 26; ++m) { v[m] = src[m * 52]; mx = fmaxf(mx, v[m]); }
    float ssum = 0.f;
#pragma unroll
    for (int m = 0; m < 26; ++m) { v[m] = __expf(v[m] - mx); ssum += v[m]; }
    float inv = 1.f / ssum;
    float* dst = dst0 + n * (26 * 52) + o;
#pragma unroll
    for (int m = 0; m < 26; ++m) dst[m * 52] = v[m] * inv;
    return;
  }
  id -= 5200;
  if (id < 3900) {  // gate coefficients: layer = id/1300, g = id%1300
    int layer = id / 1300, g = id - layer * 1300;
    const float* w = (layer == 0) ? w0 : ((layer == 1) ? w1 : w2);
    float v[16]; float mx = -3.4e38f;
#pragma unroll
    for (int k = 0; k < 16; ++k) { v[k] = w[k * 1300 + g]; mx = fmaxf(mx, v[k]); }
    float ssum = 0.f;
#pragma unroll
    for (int k = 0; k < 16; ++k) { v[k] = __expf(v[k] - mx); ssum += v[k]; }
    float inv = 1.f / ssum;
#pragma unroll
    for (int k = 0; k < 16; ++k) v[k] *= inv;
    // gates: 0, AB, A-AB, A, B-AB, B, S-AB, S, 1-S, 1-S+AB, 1-B, 1-B+AB,
    //        1-A, 1-A+AB, 1-AB, 1   (S = A+B-AB)
    float alpha = v[8] + v[9] + v[10] + v[11] + v[12] + v[13] + v[14] + v[15];
    float beta  = v[2] + v[3] + v[6] + v[7] - v[8] - v[9] - v[12] - v[13];
    float gamma = v[4] + v[5] + v[6] + v[7] - v[8] - v[9] - v[10] - v[11];
    float delta = v[1] - v[2] - v[4] - 2.f * v[6] - v[7] + v[8] + 2.f * v[9]
                + v[11] + v[13] - v[14];
    reinterpret_cast<float4*>(ws + CF_OFF)[id] =
        make_float4(alpha, beta, gamma, delta);
  }
}

// ---------------------------------------------------------------------------
// One fused layer+gate phase, in-place on a single [MT][1300] LDS buffer.
// Work unit = gate pair p (cols 2p, 2p+1 of the layer output). Each thread
// owns up to 3 pairs (p = tid + k*NT), keeps 2*MT accumulators per pair in
// registers across the barrier, then gates and writes buf[s][p] in place
// (gated output of block n lands exactly on block n's input slot).
// STRADDLE: layer-1 only (block_out=325 odd -> 4 pairs straddle blocks).
// ---------------------------------------------------------------------------
template <int NB, int BI, int BO, bool STRADDLE>
__device__ __forceinline__ void layer_phase(float* __restrict__ buf,
                                            const float* __restrict__ W,
                                            const float4* __restrict__ CF) {
  constexpr int NP = NB * BO / 2;  // = 1300 for all three layers
  constexpr int KMAX = (NP + NT - 1) / NT;  // 3
  float acc[KMAX][2][MT];
#pragma unroll
  for (int k = 0; k < KMAX; ++k)
#pragma unroll
    for (int c = 0; c < 2; ++c)
#pragma unroll
      for (int s = 0; s < MT; ++s) acc[k][c][s] = 0.f;

#pragma unroll
  for (int k = 0; k < KMAX; ++k) {
    const int p = threadIdx.x + k * NT;
    if (p < NP) {
      const int c0 = 2 * p;
      const int n = c0 / BO;
      const int o0 = c0 - n * BO;
      if (!STRADDLE || o0 != BO - 1) {
        const float* w = W + (n * BI) * BO + o0;
        const float* xin = buf + n * BI;
        for (int m = 0; m < BI; ++m) {
          float w0v, w1v;
          if (BO % 2 == 0) {
            float2 wv = *reinterpret_cast<const float2*>(w + m * BO);
            w0v = wv.x; w1v = wv.y;
          } else {
            w0v = w[m * BO]; w1v = w[m * BO + 1];
          }
#pragma unroll
          for (int s = 0; s < MT; ++s) {
            float xv = xin[s * 1300 + m];
            acc[k][0][s] = fmaf(xv, w0v, acc[k][0][s]);
            acc[k][1][s] = fmaf(xv, w1v, acc[k][1][s]);
          }
        }
      } else {
        // pair straddles a block boundary: two independent column loops
#pragma unroll
        for (int cc = 0; cc < 2; ++cc) {
          const int c = c0 + cc;
          const int nn = c / BO;
          const int oo = c - nn * BO;
          const float* w = W + (nn * BI) * BO + oo;
          const float* xin = buf + nn * BI;
          for (int m = 0; m < BI; ++m) {
            float wv = w[m * BO];
#pragma unroll
            for (int s = 0; s < MT; ++s)
              acc[k][cc][s] = fmaf(xin[s * 1300 + m], wv, acc[k][cc][s]);
          }
        }
      }
    }
  }
  __syncthreads();  // all reads of buf done
#pragma unroll
  for (int k = 0; k < KMAX; ++k) {
    const int p = threadIdx.x + k * NT;
    if (p < NP) {
      const float4 cf = CF[p];
#pragma unroll
      for (int s = 0; s < MT; ++s) {
        const float A = acc[k][0][s];
        const float Bv = acc[k][1][s];
        buf[s * 1300 + p] = cf.x + cf.y * A + cf.z * Bv + cf.w * (A * Bv);
      }
    }
  }
  __syncthreads();
}

// ---------------------------------------------------------------------------
// Fully fused network, single [MT][1300] LDS buffer (42 KB -> 3 WGs/CU).
// ---------------------------------------------------------------------------
__global__ __launch_bounds__(NT) void fused_kernel(const float* __restrict__ x,
                                                   const float* __restrict__ ws,
                                                   float* __restrict__ out,
                                                   int B) {
  extern __shared__ float smem[];
  float* buf = smem;                 // [MT][1300]
  float* lg  = smem + MT * 1300;     // [MT][10]
  const int tid = threadIdx.x;
  const int s0 = blockIdx.x * MT;

  // ---- load x tile: MT x 256 -> buf[s][0..255] (one float4 per thread) ----
  {
    int s = tid >> 6;  // 64 float4 per sample row
    int c4 = tid & 63;
    float4 v = make_float4(0.f, 0.f, 0.f, 0.f);
    if (s0 + s < B)
      v = reinterpret_cast<const float4*>(x)[(size_t)(s0 + s) * 64 + c4];
    float* r = buf + s * 1300 + c4 * 4;
    r[0] = v.x; r[1] = v.y; r[2] = v.z; r[3] = v.w;
  }
  __syncthreads();

  const float4* cf = reinterpret_cast<const float4*>(ws + CF_OFF);
  layer_phase<8, 32, 325, true>(buf, ws + C0_OFF, cf);
  layer_phase<50, 26, 52, false>(buf, ws + C1_OFF, cf + 1300);
  layer_phase<50, 26, 52, false>(buf, ws + C2_OFF, cf + 2600);

  // ---- logits: (1300) -> (10,130).sum ; then per-sample softmax ----
  if (tid < MT * 10) {
    int s = tid / 10, c = tid - s * 10;
    const float* src = buf + s * 1300 + c * 130;
    float sum = 0.f;
    for (int j = 0; j < 130; ++j) sum += src[j];
    lg[s * 10 + c] = sum;
  }
  __syncthreads();
  if (tid < MT && s0 + tid < B) {
    int s = tid;
    float mx = lg[s * 10];
#pragma unroll
    for (int c = 1; c < 10; ++c) mx = fmaxf(mx, lg[s * 10 + c]);
    float e[10]; float ssum = 0.f;
#pragma unroll
    for (int c = 0; c < 10; ++c) { e[c] = __expf(lg[s * 10 + c] - mx); ssum += e[c]; }
    float inv = 1.f / ssum;
    float* o = out + (size_t)(s0 + s) * 10;
#pragma unroll
    for (int c = 0; c < 10; ++c) o[c] = e[c] * inv;
  }
}

extern "C" void kernel_launch(void* const* d_in, const int* in_sizes, int n_in,
                              void* d_out, int out_size, void* d_ws, size_t ws_size,
                              hipStream_t stream) {
  const float* x  = (const float*)d_in[0];
  const float* c0 = (const float*)d_in[1];
  const float* w0 = (const float*)d_in[2];
  const float* c1 = (const float*)d_in[3];
  const float* w1 = (const float*)d_in[4];
  const float* c2 = (const float*)d_in[5];
  const float* w2 = (const float*)d_in[6];
  float* out = (float*)d_out;
  float* ws  = (float*)d_ws;
  const int B = in_sizes[0] / 256;

  precompute_kernel<<<46, 256, 0, stream>>>(c0, w0, c1, w1, c2, w2, ws);

  const size_t smem_bytes = (size_t)(MT * 1300 + MT * 10) * sizeof(float);
  hipFuncSetAttribute(reinterpret_cast<const void*>(fused_kernel),
                      hipFuncAttributeMaxDynamicSharedMemorySize, (int)smem_bytes);
  const int grid = (B + MT - 1) / MT;
  fused_kernel<<<grid, NT, smem_bytes, stream>>>(x, ws, out, B);
}

// Round 3
// 236.726 us; speedup vs baseline: 2.3699x; 2.3699x over previous
//
#include <hip/hip_runtime.h>
#include <cstdint>

#define NT 768
#define SAMP 64
#define NWAVE (NT / 64)

// ws float offsets — all weight layouts TRANSPOSED so a column's K-dim is contiguous
static constexpr int W0T_OFF = 0;        // w0T[n][o][m] : [8][325][32]  = 83200
static constexpr int W1T_OFF = 83200;    // w1T[k][o][m] : [50][52][26] = 67600
static constexpr int W2T_OFF = 150800;   // w2T[k][o][m] : [50][52][26] = 67600
static constexpr int CF_OFF  = 218400;   // gate coeffs float4 [3][1300] = 15600 floats

// ---------------------------------------------------------------------------
// Precompute: softmax conn weights (axis=1) stored transposed (col-major K),
// and collapse the 16-gate bank to gate(A,B) = a + b*A + c*B + d*A*B.
// ---------------------------------------------------------------------------
__global__ void precompute_kernel(const float* __restrict__ c0,
                                  const float* __restrict__ w0,
                                  const float* __restrict__ c1,
                                  const float* __restrict__ w1,
                                  const float* __restrict__ c2,
                                  const float* __restrict__ w2,
                                  float* __restrict__ ws) {
  int id = blockIdx.x * blockDim.x + threadIdx.x;
  if (id < 2600) {  // layer-1 col (n,o): softmax over m=32 (stride 325 in src)
    int n = id / 325, o = id - n * 325;
    const float* src = c0 + n * (32 * 325) + o;
    float v[32]; float mx = -3.4e38f;
#pragma unroll
    for (int m = 0; m < 32; ++m) { v[m] = src[m * 325]; mx = fmaxf(mx, v[m]); }
    float ssum = 0.f;
#pragma unroll
    for (int m = 0; m < 32; ++m) { v[m] = __expf(v[m] - mx); ssum += v[m]; }
    float inv = 1.f / ssum;
    float* dst = ws + W0T_OFF + (n * 325 + o) * 32;   // contiguous in m
#pragma unroll
    for (int m = 0; m < 32; ++m) dst[m] = v[m] * inv;
    return;
  }
  id -= 2600;
  if (id < 5200) {  // layer-2/3 col (k,o): softmax over m=26
    const float* src0 = (id < 2600) ? c1 : c2;
    float* dst0 = ws + ((id < 2600) ? W1T_OFF : W2T_OFF);
    int col = (id < 2600) ? id : id - 2600;
    int k = col / 52, o = col - k * 52;
    const float* src = src0 + k * (26 * 52) + o;
    float v[26]; float mx = -3.4e38f;
#pragma unroll
    for (int m = 0; m < 26; ++m) { v[m] = src[m * 52]; mx = fmaxf(mx, v[m]); }
    float ssum = 0.f;
#pragma unroll
    for (int m = 0; m < 26; ++m) { v[m] = __expf(v[m] - mx); ssum += v[m]; }
    float inv = 1.f / ssum;
    float* dst = dst0 + (k * 52 + o) * 26;            // contiguous in m
#pragma unroll
    for (int m = 0; m < 26; ++m) dst[m] = v[m] * inv;
    return;
  }
  id -= 5200;
  if (id < 3900) {  // gate coefficients
    int layer = id / 1300, g = id - layer * 1300;
    const float* w = (layer == 0) ? w0 : ((layer == 1) ? w1 : w2);
    float v[16]; float mx = -3.4e38f;
#pragma unroll
    for (int k = 0; k < 16; ++k) { v[k] = w[k * 1300 + g]; mx = fmaxf(mx, v[k]); }
    float ssum = 0.f;
#pragma unroll
    for (int k = 0; k < 16; ++k) { v[k] = __expf(v[k] - mx); ssum += v[k]; }
    float inv = 1.f / ssum;
#pragma unroll
    for (int k = 0; k < 16; ++k) v[k] *= inv;
    float alpha = v[8] + v[9] + v[10] + v[11] + v[12] + v[13] + v[14] + v[15];
    float beta  = v[2] + v[3] + v[6] + v[7] - v[8] - v[9] - v[12] - v[13];
    float gamma = v[4] + v[5] + v[6] + v[7] - v[8] - v[9] - v[10] - v[11];
    float delta = v[1] - v[2] - v[4] - 2.f * v[6] - v[7] + v[8] + 2.f * v[9]
                + v[11] + v[13] - v[14];
    reinterpret_cast<float4*>(ws + CF_OFF)[id] =
        make_float4(alpha, beta, gamma, delta);
  }
}

// ---------------------------------------------------------------------------
// Chain kernel: WG = 12 waves x 64 samples (sample = lane). Each wave owns
// 4-5 whole chains (chain k = gated cols [26k,26k+26) through all 3 layers).
// All dot-products run from registers with wave-uniform (scalar) weights.
// LDS: x tile [64][257], per-wave 26x64 h-buffer, 64x10 logit accumulator.
// ---------------------------------------------------------------------------
static constexpr int XB_FLOATS = 64 * 257;           // 16448
static constexpr int HB_FLOATS = NWAVE * 26 * 64;    // 19968
static constexpr int LG_FLOATS = 64 * 10;            // 640

__global__ __launch_bounds__(NT) void chain_kernel(const float* __restrict__ x,
                                                   const float* __restrict__ ws,
                                                   float* __restrict__ out,
                                                   int B) {
  extern __shared__ float smem[];
  float* xb    = smem;                         // [64][257] row-major, pad 257
  float* hbuf  = smem + XB_FLOATS;             // [NWAVE][26][64]
  float* lgbuf = smem + XB_FLOATS + HB_FLOATS; // [64][10]
  const int tid = threadIdx.x;
  const int s0 = blockIdx.x * SAMP;

  // ---- stage x tile (coalesced float4 loads), zero logit accumulator ----
  {
    const float4* x4 = reinterpret_cast<const float4*>(x);
    for (int idx = tid; idx < 64 * 64; idx += NT) {
      int r = idx >> 6, c4 = idx & 63;
      float4 v = make_float4(0.f, 0.f, 0.f, 0.f);
      if (s0 + r < B) v = x4[(size_t)(s0 + r) * 64 + c4];
      float* d = &xb[r * 257 + c4 * 4];
      d[0] = v.x; d[1] = v.y; d[2] = v.z; d[3] = v.w;
    }
    for (int i = tid; i < LG_FLOATS; i += NT) lgbuf[i] = 0.f;
  }
  __syncthreads();

  const int lane = tid & 63;
  const int w = __builtin_amdgcn_readfirstlane(tid >> 6);  // force wave-uniform
  const float* w0T = ws + W0T_OFF;
  const float* w1T = ws + W1T_OFF;
  const float* w2T = ws + W2T_OFF;
  const float4* cf = reinterpret_cast<const float4*>(ws + CF_OFF);
  float* hb = &hbuf[w * 26 * 64];

  // chains per wave: waves 0,1 -> 5; waves 2..11 -> 4   (total 50)
  const int cstart = (w < 2) ? 5 * w : 10 + 4 * (w - 2);
  const int ccnt = (w < 2) ? 5 : 4;

  for (int ci = 0; ci < ccnt; ++ci) {
    const int K = cstart + ci;
    float inp[32];

    // ---- layer 1: raw cols [52K, 52K+52) from x block(s), gate -> hb ----
    const int cs = 52 * K;
    const int nlo = cs / 325;
    const int nhi = (cs + 51) / 325;
    const int csplit = (nhi > nlo) ? 325 * nhi : cs + 52;
    {
      int base = lane * 257 + nlo * 32;
#pragma unroll
      for (int j = 0; j < 32; ++j) inp[j] = xb[base + j];
    }
    const int P0 = 26 * K;
    const int t1 = csplit >> 1;  // pairs [P0, t1) have both cols in block nlo
    for (int P = P0; P < t1; ++P) {
      const float* wp = w0T + ((nlo * 325 + (2 * P - 325 * nlo)) << 5);
      float a0 = 0.f, a1 = 0.f;
#pragma unroll
      for (int j = 0; j < 32; ++j) {
        a0 = fmaf(inp[j], wp[j], a0);
        a1 = fmaf(inp[j], wp[32 + j], a1);
      }
      float4 cv = cf[P];
      hb[(P - P0) * 64 + lane] = cv.x + cv.y * a0 + cv.z * a1 + cv.w * (a0 * a1);
    }
    if (nhi > nlo) {
      int Ps2 = t1;
      if (csplit & 1) {  // straddle pair P=t1: col csplit-1 in nlo, csplit in nhi
        const float* wp = w0T + ((nlo * 325 + (csplit - 1 - 325 * nlo)) << 5);
        float a0 = 0.f;
#pragma unroll
        for (int j = 0; j < 32; ++j) a0 = fmaf(inp[j], wp[j], a0);
        int base = lane * 257 + nhi * 32;
#pragma unroll
        for (int j = 0; j < 32; ++j) inp[j] = xb[base + j];
        const float* wq = w0T + ((nhi * 325) << 5);
        float a1 = 0.f;
#pragma unroll
        for (int j = 0; j < 32; ++j) a1 = fmaf(inp[j], wq[j], a1);
        float4 cv = cf[t1];
        hb[(t1 - P0) * 64 + lane] = cv.x + cv.y * a0 + cv.z * a1 + cv.w * (a0 * a1);
        Ps2 = t1 + 1;
      } else {
        int base = lane * 257 + nhi * 32;
#pragma unroll
        for (int j = 0; j < 32; ++j) inp[j] = xb[base + j];
      }
      for (int P = Ps2; P < P0 + 26; ++P) {
        const float* wp = w0T + ((nhi * 325 + (2 * P - 325 * nhi)) << 5);
        float a0 = 0.f, a1 = 0.f;
#pragma unroll
        for (int j = 0; j < 32; ++j) {
          a0 = fmaf(inp[j], wp[j], a0);
          a1 = fmaf(inp[j], wp[32 + j], a1);
        }
        float4 cv = cf[P];
        hb[(P - P0) * 64 + lane] = cv.x + cv.y * a0 + cv.z * a1 + cv.w * (a0 * a1);
      }
    }

    // ---- layer 2: hb -> regs -> in-place hb ----
    float hv[26];
#pragma unroll
    for (int j = 0; j < 26; ++j) hv[j] = hb[j * 64 + lane];
    {
      const float* wb = w1T + K * 52 * 26;
      const float4* cf1 = cf + 1300 + 26 * K;
      for (int q = 0; q < 26; ++q) {
        const float* wp = wb + (2 * q) * 26;
        float a0 = 0.f, a1 = 0.f;
#pragma unroll
        for (int j = 0; j < 26; ++j) {
          a0 = fmaf(hv[j], wp[j], a0);
          a1 = fmaf(hv[j], wp[26 + j], a1);
        }
        float4 cv = cf1[q];
        hb[q * 64 + lane] = cv.x + cv.y * a0 + cv.z * a1 + cv.w * (a0 * a1);
      }
    }

    // ---- layer 3 + chain partial sum ----
#pragma unroll
    for (int j = 0; j < 26; ++j) hv[j] = hb[j * 64 + lane];
    float psum = 0.f;
    {
      const float* wb = w2T + K * 52 * 26;
      const float4* cf2 = cf + 2600 + 26 * K;
      for (int q = 0; q < 26; ++q) {
        const float* wp = wb + (2 * q) * 26;
        float a0 = 0.f, a1 = 0.f;
#pragma unroll
        for (int j = 0; j < 26; ++j) {
          a0 = fmaf(hv[j], wp[j], a0);
          a1 = fmaf(hv[j], wp[26 + j], a1);
        }
        float4 cv = cf2[q];
        psum += cv.x + cv.y * a0 + cv.z * a1 + cv.w * (a0 * a1);
      }
    }
    atomicAdd(&lgbuf[lane * 10 + (K / 5)], psum);
  }
  __syncthreads();

  // ---- per-sample softmax over 10 classes (first wave) ----
  if (tid < 64 && s0 + tid < B) {
    float lg[10];
#pragma unroll
    for (int c = 0; c < 10; ++c) lg[c] = lgbuf[tid * 10 + c];
    float mx = lg[0];
#pragma unroll
    for (int c = 1; c < 10; ++c) mx = fmaxf(mx, lg[c]);
    float ssum = 0.f;
#pragma unroll
    for (int c = 0; c < 10; ++c) { lg[c] = __expf(lg[c] - mx); ssum += lg[c]; }
    float inv = 1.f / ssum;
    float* o = out + (size_t)(s0 + tid) * 10;
#pragma unroll
    for (int c = 0; c < 10; ++c) o[c] = lg[c] * inv;
  }
}

extern "C" void kernel_launch(void* const* d_in, const int* in_sizes, int n_in,
                              void* d_out, int out_size, void* d_ws, size_t ws_size,
                              hipStream_t stream) {
  const float* x  = (const float*)d_in[0];
  const float* c0 = (const float*)d_in[1];
  const float* w0 = (const float*)d_in[2];
  const float* c1 = (const float*)d_in[3];
  const float* w1 = (const float*)d_in[4];
  const float* c2 = (const float*)d_in[5];
  const float* w2 = (const float*)d_in[6];
  float* out = (float*)d_out;
  float* ws  = (float*)d_ws;
  const int B = in_sizes[0] / 256;

  precompute_kernel<<<46, 256, 0, stream>>>(c0, w0, c1, w1, c2, w2, ws);

  const size_t smem_bytes =
      (size_t)(XB_FLOATS + HB_FLOATS + LG_FLOATS) * sizeof(float);  // 148224 B
  hipFuncSetAttribute(reinterpret_cast<const void*>(chain_kernel),
                      hipFuncAttributeMaxDynamicSharedMemorySize, (int)smem_bytes);
  const int grid = (B + SAMP - 1) / SAMP;
  chain_kernel<<<grid, NT, smem_bytes, stream>>>(x, ws, out, B);
}

// Round 4
// 171.661 us; speedup vs baseline: 3.2682x; 1.3790x over previous
//
#include <hip/hip_runtime.h>
#include <cstdint>

#define NT 768
#define NWAVE 12

// ws float offsets — weights transposed so each column's K-dim is contiguous
static constexpr int W0T_OFF = 0;        // w0T[n][o][m] : [8][325][32]  = 83200
static constexpr int W1T_OFF = 83200;    // w1T[k][o][m] : [50][52][26] = 67600
static constexpr int W2T_OFF = 150800;   // w2T[k][o][m] : [50][52][26] = 67600
static constexpr int CF_OFF  = 218400;   // gate coeffs float4 [3][1300] = 15600 floats
static constexpr int LG_OFF  = 234000;   // logits [B][10] f32 = 163840 floats

// ---------------------------------------------------------------------------
// Precompute: softmax conn weights (axis=1), stored transposed, and collapse
// the 16-gate bank to gate(A,B) = a + b*A + c*B + d*A*B.
// ---------------------------------------------------------------------------
__global__ void precompute_kernel(const float* __restrict__ c0,
                                  const float* __restrict__ w0,
                                  const float* __restrict__ c1,
                                  const float* __restrict__ w1,
                                  const float* __restrict__ c2,
                                  const float* __restrict__ w2,
                                  float* __restrict__ ws) {
  int id = blockIdx.x * blockDim.x + threadIdx.x;
  if (id < 2600) {  // layer-1 col (n,o): softmax over m=32 (stride 325 in src)
    int n = id / 325, o = id - n * 325;
    const float* src = c0 + n * (32 * 325) + o;
    float v[32]; float mx = -3.4e38f;
#pragma unroll
    for (int m = 0; m < 32; ++m) { v[m] = src[m * 325]; mx = fmaxf(mx, v[m]); }
    float ssum = 0.f;
#pragma unroll
    for (int m = 0; m < 32; ++m) { v[m] = __expf(v[m] - mx); ssum += v[m]; }
    float inv = 1.f / ssum;
    float* dst = ws + W0T_OFF + (n * 325 + o) * 32;
#pragma unroll
    for (int m = 0; m < 32; ++m) dst[m] = v[m] * inv;
    return;
  }
  id -= 2600;
  if (id < 5200) {  // layer-2/3 col (k,o): softmax over m=26
    const float* src0 = (id < 2600) ? c1 : c2;
    float* dst0 = ws + ((id < 2600) ? W1T_OFF : W2T_OFF);
    int col = (id < 2600) ? id : id - 2600;
    int k = col / 52, o = col - k * 52;
    const float* src = src0 + k * (26 * 52) + o;
    float v[26]; float mx = -3.4e38f;
#pragma unroll
    for (int m = 0; m < 26; ++m) { v[m] = src[m * 52]; mx = fmaxf(mx, v[m]); }
    float ssum = 0.f;
#pragma unroll
    for (int m = 0; m < 26; ++m) { v[m] = __expf(v[m] - mx); ssum += v[m]; }
    float inv = 1.f / ssum;
    float* dst = dst0 + (k * 52 + o) * 26;
#pragma unroll
    for (int m = 0; m < 26; ++m) dst[m] = v[m] * inv;
    return;
  }
  id -= 5200;
  if (id < 3900) {  // gate coefficients
    int layer = id / 1300, g = id - layer * 1300;
    const float* w = (layer == 0) ? w0 : ((layer == 1) ? w1 : w2);
    float v[16]; float mx = -3.4e38f;
#pragma unroll
    for (int k = 0; k < 16; ++k) { v[k] = w[k * 1300 + g]; mx = fmaxf(mx, v[k]); }
    float ssum = 0.f;
#pragma unroll
    for (int k = 0; k < 16; ++k) { v[k] = __expf(v[k] - mx); ssum += v[k]; }
    float inv = 1.f / ssum;
#pragma unroll
    for (int k = 0; k < 16; ++k) v[k] *= inv;
    float alpha = v[8] + v[9] + v[10] + v[11] + v[12] + v[13] + v[14] + v[15];
    float beta  = v[2] + v[3] + v[6] + v[7] - v[8] - v[9] - v[12] - v[13];
    float gamma = v[4] + v[5] + v[6] + v[7] - v[8] - v[9] - v[10] - v[11];
    float delta = v[1] - v[2] - v[4] - 2.f * v[6] - v[7] + v[8] + 2.f * v[9]
                + v[11] + v[13] - v[14];
    reinterpret_cast<float4*>(ws + CF_OFF)[id] =
        make_float4(alpha, beta, gamma, delta);
  }
}

__device__ __forceinline__ float gate4(float4 cv, float a0, float a1) {
  return fmaf(cv.w, a0 * a1, fmaf(cv.z, a1, fmaf(cv.y, a0, cv.x)));
}

// ---------------------------------------------------------------------------
// Chain kernel: grid = 2 WGs per 64-sample block (half = chains 0-24 / 25-49,
// i.e. classes 5h..5h+4). WG = 12 waves, sample = lane. Chains fully
// register-resident (h[26]/h2[26], static indexing); weights scalar-loaded.
// LDS = x tile [64][257] + [64][5] logit accum = 67 KB -> 2 WGs/CU, 24 waves.
// ---------------------------------------------------------------------------
static constexpr int XB_FLOATS = 64 * 257;  // 16448
static constexpr int LG_FLOATS = 64 * 5;    // 320

__global__ __launch_bounds__(NT, 6) void chain_kernel(
    const float* __restrict__ x, const float* __restrict__ ws,
    float* __restrict__ lgout, int B) {
  extern __shared__ float smem[];
  float* xb  = smem;              // [64][257] (pad to 257: stride%32==1)
  float* lgb = smem + XB_FLOATS;  // [64][5]
  const int tid = threadIdx.x;
  const int sblk = blockIdx.x >> 1;
  const int half = blockIdx.x & 1;
  const int s0 = sblk * 64;

  // ---- stage x tile (coalesced float4 loads), zero logit accumulator ----
  {
    const float4* x4 = reinterpret_cast<const float4*>(x);
    for (int idx = tid; idx < 64 * 64; idx += NT) {
      int r = idx >> 6, c4 = idx & 63;
      float4 v = make_float4(0.f, 0.f, 0.f, 0.f);
      if (s0 + r < B) v = x4[(size_t)(s0 + r) * 64 + c4];
      float* d = &xb[r * 257 + c4 * 4];
      d[0] = v.x; d[1] = v.y; d[2] = v.z; d[3] = v.w;
    }
    for (int i = tid; i < LG_FLOATS; i += NT) lgb[i] = 0.f;
  }
  __syncthreads();

  const int lane = tid & 63;
  const int wv = __builtin_amdgcn_readfirstlane(tid >> 6);
  const float* w0T = ws + W0T_OFF;
  const float* w1T = ws + W1T_OFF;
  const float* w2T = ws + W2T_OFF;
  const float4* cf = reinterpret_cast<const float4*>(ws + CF_OFF);
  const float* xrow = xb + lane * 257;

  // 25 chains over 12 waves: wave 0 -> 3 chains, waves 1-11 -> 2 chains
  const int cnt = (wv == 0) ? 3 : 2;
  const int cst = 25 * half + ((wv == 0) ? 0 : (1 + 2 * wv));

  for (int ci = 0; ci < cnt; ++ci) {
    const int K = cst + ci;
    const int cs = 52 * K;
    const int nlo = cs / 325;
    const int nhi = (cs + 51) / 325;
    const int split = (nhi > nlo) ? (325 * nhi - cs) : 52;  // rel col of switch
    const int t1 = split >> 1;   // pairs fully in block nlo
    const int odd = split & 1;   // pair t1 straddles the boundary
    const float4* cfK = cf + 26 * K;

    float h[26];
    float inp[32];
#pragma unroll
    for (int j = 0; j < 32; ++j) inp[j] = xrow[nlo * 32 + j];

    // ---- layer 1, phase A (block nlo) ----
#pragma unroll
    for (int P = 0; P < 26; ++P) {
      if (P < t1) {
        const float* wp = w0T + (size_t)(nlo * 325 + (cs - 325 * nlo) + 2 * P) * 32;
        float a0 = 0.f, a1 = 0.f;
#pragma unroll
        for (int j = 0; j < 32; ++j) {
          a0 = fmaf(inp[j], wp[j], a0);
          a1 = fmaf(inp[j], wp[32 + j], a1);
        }
        h[P] = gate4(cfK[P], a0, a1);
      }
    }
    // ---- straddle + phase B (block nhi) ----
    if (nhi > nlo) {
      float a0s = 0.f, a1s = 0.f, gs = 0.f;
      if (odd) {
        const float* wp = w0T + (size_t)(nlo * 325 + (cs - 325 * nlo) + 2 * t1) * 32;
#pragma unroll
        for (int j = 0; j < 32; ++j) a0s = fmaf(inp[j], wp[j], a0s);
      }
#pragma unroll
      for (int j = 0; j < 32; ++j) inp[j] = xrow[nhi * 32 + j];
      if (odd) {
        const float* wq = w0T + (size_t)(nhi * 325) * 32;
#pragma unroll
        for (int j = 0; j < 32; ++j) a1s = fmaf(inp[j], wq[j], a1s);
        gs = gate4(cf[26 * K + t1], a0s, a1s);
      }
#pragma unroll
      for (int P = 0; P < 26; ++P) {
        if (P >= t1 + odd) {
          const float* wp = w0T + (size_t)(nhi * 325 + (cs - 325 * nhi) + 2 * P) * 32;
          float a0 = 0.f, a1 = 0.f;
#pragma unroll
          for (int j = 0; j < 32; ++j) {
            a0 = fmaf(inp[j], wp[j], a0);
            a1 = fmaf(inp[j], wp[32 + j], a1);
          }
          h[P] = gate4(cfK[P], a0, a1);
        }
      }
      if (odd) {  // static-index select to avoid dynamic h[t1] write
#pragma unroll
        for (int P = 0; P < 26; ++P)
          if (P == t1) h[P] = gs;
      }
    }

    // ---- layer 2 (register-resident, fully unrolled) ----
    float h2[26];
    {
      const float* wb = w1T + (size_t)K * (52 * 26);
      const float4* cf1 = cf + 1300 + 26 * K;
#pragma unroll
      for (int q = 0; q < 26; ++q) {
        const float* wp = wb + q * 52;
        float a0 = 0.f, a1 = 0.f;
#pragma unroll
        for (int j = 0; j < 26; ++j) {
          a0 = fmaf(h[j], wp[j], a0);
          a1 = fmaf(h[j], wp[26 + j], a1);
        }
        h2[q] = gate4(cf1[q], a0, a1);
      }
    }

    // ---- layer 3 + chain partial sum (rolled outer, unrolled inner) ----
    float psum = 0.f;
    {
      const float* wb = w2T + (size_t)K * (52 * 26);
      const float4* cf2 = cf + 2600 + 26 * K;
#pragma unroll 1
      for (int q = 0; q < 26; ++q) {
        const float* wp = wb + q * 52;
        float a0 = 0.f, a1 = 0.f;
#pragma unroll
        for (int j = 0; j < 26; ++j) {
          a0 = fmaf(h2[j], wp[j], a0);
          a1 = fmaf(h2[j], wp[26 + j], a1);
        }
        float4 cv = cf2[q];
        psum += gate4(cv, a0, a1);
      }
    }
    atomicAdd(&lgb[lane * 5 + (K / 5 - 5 * half)], psum);
  }
  __syncthreads();

  // ---- write this half's 5 classes (disjoint across WGs, no atomics) ----
  for (int i = tid; i < LG_FLOATS; i += NT) {
    int s = i / 5, c = i - (i / 5) * 5;
    if (s0 + s < B) lgout[(size_t)(s0 + s) * 10 + 5 * half + c] = lgb[i];
  }
}

// ---------------------------------------------------------------------------
// Finalize: per-sample 10-way softmax.
// ---------------------------------------------------------------------------
__global__ __launch_bounds__(256) void softmax_kernel(
    const float* __restrict__ lgin, float* __restrict__ out, int B) {
  int s = blockIdx.x * 256 + threadIdx.x;
  if (s >= B) return;
  float lg[10];
#pragma unroll
  for (int c = 0; c < 10; ++c) lg[c] = lgin[(size_t)s * 10 + c];
  float mx = lg[0];
#pragma unroll
  for (int c = 1; c < 10; ++c) mx = fmaxf(mx, lg[c]);
  float ssum = 0.f;
#pragma unroll
  for (int c = 0; c < 10; ++c) { lg[c] = __expf(lg[c] - mx); ssum += lg[c]; }
  float inv = 1.f / ssum;
  float* o = out + (size_t)s * 10;
#pragma unroll
  for (int c = 0; c < 10; ++c) o[c] = lg[c] * inv;
}

extern "C" void kernel_launch(void* const* d_in, const int* in_sizes, int n_in,
                              void* d_out, int out_size, void* d_ws, size_t ws_size,
                              hipStream_t stream) {
  const float* x  = (const float*)d_in[0];
  const float* c0 = (const float*)d_in[1];
  const float* w0 = (const float*)d_in[2];
  const float* c1 = (const float*)d_in[3];
  const float* w1 = (const float*)d_in[4];
  const float* c2 = (const float*)d_in[5];
  const float* w2 = (const float*)d_in[6];
  float* out = (float*)d_out;
  float* ws  = (float*)d_ws;
  const int B = in_sizes[0] / 256;

  precompute_kernel<<<46, 256, 0, stream>>>(c0, w0, c1, w1, c2, w2, ws);

  const size_t smem_bytes = (size_t)(XB_FLOATS + LG_FLOATS) * sizeof(float);
  hipFuncSetAttribute(reinterpret_cast<const void*>(chain_kernel),
                      hipFuncAttributeMaxDynamicSharedMemorySize, (int)smem_bytes);
  const int nblk = (B + 63) / 64;
  chain_kernel<<<nblk * 2, NT, smem_bytes, stream>>>(x, ws, ws + LG_OFF, B);
  softmax_kernel<<<(B + 255) / 256, 256, 0, stream>>>(ws + LG_OFF, out, B);
}

// Round 5
// 164.486 us; speedup vs baseline: 3.4108x; 1.0436x over previous
//
#include <hip/hip_runtime.h>
#include <cstdint>

#define NT 512

// ws float offsets — weights transposed so each column's K-dim is contiguous
static constexpr int W0T_OFF = 0;        // w0T[n][o][m] : [8][325][32]  = 83200
static constexpr int W1T_OFF = 83200;    // w1T[k][o][m] : [50][52][26] = 67600
static constexpr int W2T_OFF = 150800;   // w2T[k][o][m] : [50][52][26] = 67600
static constexpr int CF_OFF  = 218400;   // gate coeffs float4 [3][1300] = 15600 floats
static constexpr int LG_OFF  = 234000;   // logits [B][10] f32

// ---------------------------------------------------------------------------
// Precompute: softmax conn weights (axis=1), stored transposed, and collapse
// the 16-gate bank to gate(A,B) = a + b*A + c*B + d*A*B.
// ---------------------------------------------------------------------------
__global__ void precompute_kernel(const float* __restrict__ c0,
                                  const float* __restrict__ w0,
                                  const float* __restrict__ c1,
                                  const float* __restrict__ w1,
                                  const float* __restrict__ c2,
                                  const float* __restrict__ w2,
                                  float* __restrict__ ws) {
  int id = blockIdx.x * blockDim.x + threadIdx.x;
  if (id < 2600) {  // layer-1 col (n,o): softmax over m=32 (stride 325 in src)
    int n = id / 325, o = id - n * 325;
    const float* src = c0 + n * (32 * 325) + o;
    float v[32]; float mx = -3.4e38f;
#pragma unroll
    for (int m = 0; m < 32; ++m) { v[m] = src[m * 325]; mx = fmaxf(mx, v[m]); }
    float ssum = 0.f;
#pragma unroll
    for (int m = 0; m < 32; ++m) { v[m] = __expf(v[m] - mx); ssum += v[m]; }
    float inv = 1.f / ssum;
    float* dst = ws + W0T_OFF + (n * 325 + o) * 32;
#pragma unroll
    for (int m = 0; m < 32; ++m) dst[m] = v[m] * inv;
    return;
  }
  id -= 2600;
  if (id < 5200) {  // layer-2/3 col (k,o): softmax over m=26
    const float* src0 = (id < 2600) ? c1 : c2;
    float* dst0 = ws + ((id < 2600) ? W1T_OFF : W2T_OFF);
    int col = (id < 2600) ? id : id - 2600;
    int k = col / 52, o = col - k * 52;
    const float* src = src0 + k * (26 * 52) + o;
    float v[26]; float mx = -3.4e38f;
#pragma unroll
    for (int m = 0; m < 26; ++m) { v[m] = src[m * 52]; mx = fmaxf(mx, v[m]); }
    float ssum = 0.f;
#pragma unroll
    for (int m = 0; m < 26; ++m) { v[m] = __expf(v[m] - mx); ssum += v[m]; }
    float inv = 1.f / ssum;
    float* dst = dst0 + (k * 52 + o) * 26;
#pragma unroll
    for (int m = 0; m < 26; ++m) dst[m] = v[m] * inv;
    return;
  }
  id -= 5200;
  if (id < 3900) {  // gate coefficients
    int layer = id / 1300, g = id - layer * 1300;
    const float* w = (layer == 0) ? w0 : ((layer == 1) ? w1 : w2);
    float v[16]; float mx = -3.4e38f;
#pragma unroll
    for (int k = 0; k < 16; ++k) { v[k] = w[k * 1300 + g]; mx = fmaxf(mx, v[k]); }
    float ssum = 0.f;
#pragma unroll
    for (int k = 0; k < 16; ++k) { v[k] = __expf(v[k] - mx); ssum += v[k]; }
    float inv = 1.f / ssum;
#pragma unroll
    for (int k = 0; k < 16; ++k) v[k] *= inv;
    float alpha = v[8] + v[9] + v[10] + v[11] + v[12] + v[13] + v[14] + v[15];
    float beta  = v[2] + v[3] + v[6] + v[7] - v[8] - v[9] - v[12] - v[13];
    float gamma = v[4] + v[5] + v[6] + v[7] - v[8] - v[9] - v[10] - v[11];
    float delta = v[1] - v[2] - v[4] - 2.f * v[6] - v[7] + v[8] + 2.f * v[9]
                + v[11] + v[13] - v[14];
    reinterpret_cast<float4*>(ws + CF_OFF)[id] =
        make_float4(alpha, beta, gamma, delta);
  }
}

__device__ __forceinline__ float gate4(float4 cv, float a0, float a1) {
  return fmaf(cv.w, a0 * a1, fmaf(cv.z, a1, fmaf(cv.y, a0, cv.x)));
}

// ---------------------------------------------------------------------------
// Chain kernel, 4 WGs per 64-sample tile (class-aligned quarter-split):
//   q = blockIdx&3: half = q>>1 (chains 0-24 / 25-49), sub = q&1
//   sub0 = 15 chains (3 classes), sub1 = 10 chains (2 classes).
// Grid = 256*4 = 1024 WGs -> 4 resident WGs/CU * 8 waves = 32 waves (full).
// Each WG stages only the 2-3 x-blocks its chains read (<=96 cols, 26 KB).
// ---------------------------------------------------------------------------
static constexpr int XB_STRIDE = 98;              // 96 cols + 2 pad (bank: 2l+j)
static constexpr int XB_FLOATS = 64 * XB_STRIDE;  // 6272
static constexpr int LG_FLOATS = 64 * 3;          // max 3 classes per WG

__global__ __launch_bounds__(NT, 8) void chain_kernel(
    const float* __restrict__ x, const float* __restrict__ ws,
    float* __restrict__ lgout, int B) {
  extern __shared__ float smem[];
  float* xb  = smem;              // [64][98]
  float* lgb = smem + XB_FLOATS;  // [64][nlgc]
  const int tid = threadIdx.x;
  const int bid = blockIdx.x;
  const int tile = bid >> 2;
  const int half = (bid >> 1) & 1;
  const int sub = bid & 1;
  const int s0 = tile * 64;

  const int base = half * 25 + sub * 15;  // first chain of this WG
  const int cnt_wg = sub ? 10 : 15;
  const int clsbase = half * 5 + sub * 3;
  const int nlgc = sub ? 2 : 3;
  const int bl0 = (52 * base) / 325;                        // first x-block
  const int nb = (52 * (base + cnt_wg) - 1) / 325 - bl0 + 1;  // 2 or 3

  // ---- stage needed x-blocks ([64][nb*32] <- coalesced float4), zero lgb ----
  {
    const float4* x4 = reinterpret_cast<const float4*>(x);
    const int rowq = nb * 8;  // float4s per row
    for (int idx = tid; idx < 64 * rowq; idx += NT) {
      int r = idx / rowq, c4 = idx - r * rowq;
      float4 v = make_float4(0.f, 0.f, 0.f, 0.f);
      if (s0 + r < B) v = x4[(size_t)(s0 + r) * 64 + bl0 * 8 + c4];
      float* d = &xb[r * XB_STRIDE + c4 * 4];
      d[0] = v.x; d[1] = v.y; d[2] = v.z; d[3] = v.w;
    }
    for (int i = tid; i < 64 * nlgc; i += NT) lgb[i] = 0.f;
  }
  __syncthreads();

  const int lane = tid & 63;
  const int wv = __builtin_amdgcn_readfirstlane(tid >> 6);  // 0..7
  const float* w0T = ws + W0T_OFF;
  const float* w1T = ws + W1T_OFF;
  const float* w2T = ws + W2T_OFF;
  const float4* cf = reinterpret_cast<const float4*>(ws + CF_OFF);
  const float* xrow = xb + lane * XB_STRIDE;

  // chains per wave (critical path 2): sub0: 2,2,2,2,2,2,2,1; sub1: 2,2,1*6
  int cw, start;
  if (sub == 0) { cw = (wv < 7) ? 2 : 1; start = 2 * wv; }
  else          { cw = (wv < 2) ? 2 : 1; start = (wv < 2) ? 2 * wv : 2 + wv; }

#pragma unroll 1
  for (int ci = 0; ci < cw; ++ci) {
    const int K = base + start + ci;
    const int cs = 52 * K;
    const int nlo = cs / 325;
    const int nhi = (cs + 51) / 325;
    const int split = (nhi > nlo) ? (325 * nhi - cs) : 52;
    const int t1 = split >> 1;
    const int odd = split & 1;
    const float4* cfK = cf + 26 * K;

    float h[26];
    float inp[32];
#pragma unroll
    for (int j = 0; j < 32; ++j) inp[j] = xrow[(nlo - bl0) * 32 + j];

    // ---- layer 1, phase A (block nlo) ----
#pragma unroll
    for (int P = 0; P < 26; ++P) {
      if (P < t1) {
        const float* wp = w0T + (size_t)(nlo * 325 + (cs - 325 * nlo) + 2 * P) * 32;
        float a0 = 0.f, a1 = 0.f;
#pragma unroll
        for (int j = 0; j < 32; ++j) {
          a0 = fmaf(inp[j], wp[j], a0);
          a1 = fmaf(inp[j], wp[32 + j], a1);
        }
        h[P] = gate4(cfK[P], a0, a1);
      }
    }
    // ---- straddle + phase B (block nhi) ----
    if (nhi > nlo) {
      float a0s = 0.f, a1s = 0.f, gs = 0.f;
      if (odd) {
        const float* wp = w0T + (size_t)(nlo * 325 + (cs - 325 * nlo) + 2 * t1) * 32;
#pragma unroll
        for (int j = 0; j < 32; ++j) a0s = fmaf(inp[j], wp[j], a0s);
      }
#pragma unroll
      for (int j = 0; j < 32; ++j) inp[j] = xrow[(nhi - bl0) * 32 + j];
      if (odd) {
        const float* wq = w0T + (size_t)(nhi * 325) * 32;
#pragma unroll
        for (int j = 0; j < 32; ++j) a1s = fmaf(inp[j], wq[j], a1s);
        gs = gate4(cf[26 * K + t1], a0s, a1s);
      }
#pragma unroll
      for (int P = 0; P < 26; ++P) {
        if (P >= t1 + odd) {
          const float* wp = w0T + (size_t)(nhi * 325 + (cs - 325 * nhi) + 2 * P) * 32;
          float a0 = 0.f, a1 = 0.f;
#pragma unroll
          for (int j = 0; j < 32; ++j) {
            a0 = fmaf(inp[j], wp[j], a0);
            a1 = fmaf(inp[j], wp[32 + j], a1);
          }
          h[P] = gate4(cfK[P], a0, a1);
        }
      }
      if (odd) {  // static-index select (avoid dynamic h[t1] write)
#pragma unroll
        for (int P = 0; P < 26; ++P)
          if (P == t1) h[P] = gs;
      }
    }

    // ---- layer 2 (register-resident, fully unrolled: static h2 writes) ----
    float h2[26];
    {
      const float* wb = w1T + (size_t)K * (52 * 26);
      const float4* cf1 = cf + 1300 + 26 * K;
#pragma unroll
      for (int q = 0; q < 26; ++q) {
        const float* wp = wb + q * 52;
        float a0 = 0.f, a1 = 0.f;
#pragma unroll
        for (int j = 0; j < 26; ++j) {
          a0 = fmaf(h[j], wp[j], a0);
          a1 = fmaf(h[j], wp[26 + j], a1);
        }
        h2[q] = gate4(cf1[q], a0, a1);
      }
    }

    // ---- layer 3 + chain partial sum ----
    float psum = 0.f;
    {
      const float* wb = w2T + (size_t)K * (52 * 26);
      const float4* cf2 = cf + 2600 + 26 * K;
#pragma unroll 2
      for (int q = 0; q < 26; ++q) {
        const float* wp = wb + q * 52;
        float a0 = 0.f, a1 = 0.f;
#pragma unroll
        for (int j = 0; j < 26; ++j) {
          a0 = fmaf(h2[j], wp[j], a0);
          a1 = fmaf(h2[j], wp[26 + j], a1);
        }
        psum += gate4(cf2[q], a0, a1);
      }
    }
    atomicAdd(&lgb[lane * nlgc + (K / 5 - clsbase)], psum);
  }
  __syncthreads();

  // ---- write this WG's classes (disjoint across WGs, deterministic) ----
  for (int i = tid; i < 64 * nlgc; i += NT) {
    int s = i / nlgc, c = i - (i / nlgc) * nlgc;
    if (s0 + s < B) lgout[(size_t)(s0 + s) * 10 + clsbase + c] = lgb[i];
  }
}

// ---------------------------------------------------------------------------
// Finalize: per-sample 10-way softmax.
// ---------------------------------------------------------------------------
__global__ __launch_bounds__(256) void softmax_kernel(
    const float* __restrict__ lgin, float* __restrict__ out, int B) {
  int s = blockIdx.x * 256 + threadIdx.x;
  if (s >= B) return;
  float lg[10];
#pragma unroll
  for (int c = 0; c < 10; ++c) lg[c] = lgin[(size_t)s * 10 + c];
  float mx = lg[0];
#pragma unroll
  for (int c = 1; c < 10; ++c) mx = fmaxf(mx, lg[c]);
  float ssum = 0.f;
#pragma unroll
  for (int c = 0; c < 10; ++c) { lg[c] = __expf(lg[c] - mx); ssum += lg[c]; }
  float inv = 1.f / ssum;
  float* o = out + (size_t)s * 10;
#pragma unroll
  for (int c = 0; c < 10; ++c) o[c] = lg[c] * inv;
}

extern "C" void kernel_launch(void* const* d_in, const int* in_sizes, int n_in,
                              void* d_out, int out_size, void* d_ws, size_t ws_size,
                              hipStream_t stream) {
  const float* x  = (const float*)d_in[0];
  const float* c0 = (const float*)d_in[1];
  const float* w0 = (const float*)d_in[2];
  const float* c1 = (const float*)d_in[3];
  const float* w1 = (const float*)d_in[4];
  const float* c2 = (const float*)d_in[5];
  const float* w2 = (const float*)d_in[6];
  float* out = (float*)d_out;
  float* ws  = (float*)d_ws;
  const int B = in_sizes[0] / 256;

  precompute_kernel<<<46, 256, 0, stream>>>(c0, w0, c1, w1, c2, w2, ws);

  const size_t smem_bytes = (size_t)(XB_FLOATS + LG_FLOATS) * sizeof(float);
  hipFuncSetAttribute(reinterpret_cast<const void*>(chain_kernel),
                      hipFuncAttributeMaxDynamicSharedMemorySize, (int)smem_bytes);
  const int nblk = (B + 63) / 64;
  chain_kernel<<<nblk * 4, NT, smem_bytes, stream>>>(x, ws, ws + LG_OFF, B);
  softmax_kernel<<<(B + 255) / 256, 256, 0, stream>>>(ws + LG_OFF, out, B);
}